// Round 6
// baseline (416.797 us; speedup 1.0000x reference)
//
#include <hip/hip_runtime.h>
#include <stdint.h>

#define DIM   1024
#define NH    16
#define HD    64
#define SEQ   2048
#define BATCH 2
#define MROWS 4096   // B*N
#define MLPD  4096
#define LN_EPS 1e-5f
// attn scale 1/8 with log2(e) folded in: exp(x) = exp2(x*L2E)
#define QSCALE 0.18033688011112042f

typedef _Float16 f16;
typedef _Float16 half8 __attribute__((ext_vector_type(8)));
typedef _Float16 half4 __attribute__((ext_vector_type(4)));
typedef float f32x4 __attribute__((ext_vector_type(4)));

__device__ __forceinline__ void async_cp16(const void* g, void* l) {
  __builtin_amdgcn_global_load_lds(
      (const __attribute__((address_space(1))) unsigned int*)g,
      (__attribute__((address_space(3))) unsigned int*)l, 16, 0, 0);
}

// ---------- fused fp32 -> fp16 convert of all 4 weight matrices ----------
__global__ __launch_bounds__(256) void cvt_all_kernel(
    const float* __restrict__ w0, const float* __restrict__ w1,
    const float* __restrict__ w2, const float* __restrict__ w3,
    f16* __restrict__ d0, f16* __restrict__ d1, f16* __restrict__ d2,
    f16* __restrict__ d3) {
  int blk = blockIdx.x;
  const float* s;
  f16* d;
  int base;
  if (blk < 3072)      { s = w0; d = d0; base = blk; }
  else if (blk < 4096) { s = w1; d = d1; base = blk - 3072; }
  else if (blk < 8192) { s = w2; d = d2; base = blk - 4096; }
  else                 { s = w3; d = d3; base = blk - 8192; }
  int i = (base * 256 + threadIdx.x) * 4;
  float4 v = *(const float4*)(s + i);
  half4 o = { (f16)v.x, (f16)v.y, (f16)v.z, (f16)v.w };
  *(half4*)(d + i) = o;
}

// ---------- LayerNorm: fp32 [rows,1024] -> fp16 ----------
__global__ __launch_bounds__(256) void ln_kernel(const float* __restrict__ x,
    const float* __restrict__ w, const float* __restrict__ b, f16* __restrict__ out) {
  __shared__ float red[8];
  int row = blockIdx.x, t = threadIdx.x;
  const float4 v = ((const float4*)(x + (size_t)row * DIM))[t];
  float s1 = v.x + v.y + v.z + v.w;
  float s2 = v.x * v.x + v.y * v.y + v.z * v.z + v.w * v.w;
#pragma unroll
  for (int m = 32; m; m >>= 1) { s1 += __shfl_xor(s1, m); s2 += __shfl_xor(s2, m); }
  if ((t & 63) == 0) { red[t >> 6] = s1; red[4 + (t >> 6)] = s2; }
  __syncthreads();
  s1 = red[0] + red[1] + red[2] + red[3];
  s2 = red[4] + red[5] + red[6] + red[7];
  float mu = s1 * (1.f / DIM);
  float rs = rsqrtf(s2 * (1.f / DIM) - mu * mu + LN_EPS);
  float4 wv = ((const float4*)w)[t];
  float4 bv = ((const float4*)b)[t];
  half4 o = { (f16)((v.x - mu) * rs * wv.x + bv.x), (f16)((v.y - mu) * rs * wv.y + bv.y),
              (f16)((v.z - mu) * rs * wv.z + bv.z), (f16)((v.w - mu) * rs * wv.w + bv.w) };
  ((half4*)(out + (size_t)row * DIM))[t] = o;
}

// ---------- GEMM  C[M,N] = A[M,K] @ W[N,K]^T  (both K-major fp16) ----------
// MODE 0: QKV scatter: q*QSCALE, k -> [B,H,N,64]; v -> TRANSPOSED [B,H,64,N]
// MODE 1: out = acc + bias[col] + resid[row,col]  (fp32 out, N-stride DIM)
// MODE 2: out = f16(silu(acc + bias[col]))        (fp16 out, stride MLPD)
// Wave layout: TN=128 -> 2x2 waves, TM must be 128; TN=64 -> 4x1 waves, TM 64 or 128.
template <int MODE, int TM, int TN>
__global__ __launch_bounds__(256, (TN == 64) ? 4 : 1) void gemm_bt(
    const f16* __restrict__ A, const f16* __restrict__ W,
    const float* __restrict__ bias, const float* __restrict__ resid,
    float* __restrict__ outf, f16* __restrict__ outq, f16* __restrict__ outk,
    f16* __restrict__ outv, int K) {
  constexpr int IT = (TN == 128) ? (TM / 32) : (TM / 64);  // i-tiles per wave
  constexpr int MSUB = IT * 16;                            // m-rows per wave
  __shared__ __align__(16) f16 As[TM * 64];
  __shared__ __align__(16) f16 Bs[TN * 64];
  const int t = threadIdx.x;
  const int wave = t >> 6, lane = t & 63;
  const int n16 = lane & 15, quad = lane >> 4;
  const int tile_m = blockIdx.y * TM, tile_n = blockIdx.x * TN;
  const int wm = (TN == 128) ? (wave >> 1) : wave;
  const int wn = (TN == 128) ? (wave & 1) : 0;
  const int srow = lane >> 3, spos = lane & 7;
  const f32x4 zero4 = {0.f, 0.f, 0.f, 0.f};

  f32x4 acc[IT][4];
#pragma unroll
  for (int i = 0; i < IT; i++)
#pragma unroll
    for (int j = 0; j < 4; j++) acc[i][j] = zero4;

  for (int k0 = 0; k0 < K; k0 += 64) {
    // stage A-tile (TMx64) and B-tile (TNx64), XOR-swizzled 16B chunks
#pragma unroll
    for (int q = 0; q < TM / 32; q++) {
      int r = q * 32 + wave * 8 + srow;
      int c = spos ^ (r & 7);
      async_cp16(A + (size_t)(tile_m + r) * K + k0 + c * 8, &As[q * 2048 + wave * 512]);
    }
#pragma unroll
    for (int q = 0; q < TN / 32; q++) {
      int r = q * 32 + wave * 8 + srow;
      int c = spos ^ (r & 7);
      async_cp16(W + (size_t)(tile_n + r) * K + k0 + c * 8, &Bs[q * 2048 + wave * 512]);
    }
    __syncthreads();
#pragma unroll
    for (int kk = 0; kk < 2; kk++) {
      half8 af[IT], bfr[4];
#pragma unroll
      for (int i = 0; i < IT; i++) {
        int row = wm * MSUB + i * 16 + n16;
        int c = (kk * 4 + quad) ^ (row & 7);
        af[i] = *(const half8*)&As[row * 64 + c * 8];
      }
#pragma unroll
      for (int j = 0; j < 4; j++) {
        int row = wn * 64 + j * 16 + n16;
        int c = (kk * 4 + quad) ^ (row & 7);
        bfr[j] = *(const half8*)&Bs[row * 64 + c * 8];
      }
#pragma unroll
      for (int i = 0; i < IT; i++)
#pragma unroll
        for (int j = 0; j < 4; j++)
          acc[i][j] = __builtin_amdgcn_mfma_f32_16x16x32_f16(af[i], bfr[j], acc[i][j], 0, 0, 0);
    }
    __syncthreads();
  }

#pragma unroll
  for (int i = 0; i < IT; i++) {
#pragma unroll
    for (int j = 0; j < 4; j++) {
      int gcol = tile_n + wn * 64 + j * 16 + n16;
      int grow0 = tile_m + wm * MSUB + i * 16 + quad * 4;
      if constexpr (MODE == 0) {
        int tsel = gcol >> 10, h = (gcol >> 6) & 15, d = gcol & 63;
        int bb = grow0 >> 11, nn0 = grow0 & 2047;
        if (tsel == 2) {
          // V transposed: vt[((bb*NH+h)*HD+d)*SEQ + nn], 4 consecutive nn
          half4 o;
#pragma unroll
          for (int r = 0; r < 4; r++) o[r] = (f16)acc[i][j][r];
          *(half4*)&outv[(((size_t)bb * NH + h) * HD + d) * SEQ + nn0] = o;
        } else {
          f16* dst = (tsel == 0) ? outq : outk;
          float sc = (tsel == 0) ? QSCALE : 1.0f;
#pragma unroll
          for (int r = 0; r < 4; r++)
            dst[(((size_t)bb * NH + h) * SEQ + nn0 + r) * HD + d] = (f16)(acc[i][j][r] * sc);
        }
      } else if constexpr (MODE == 1) {
#pragma unroll
        for (int r = 0; r < 4; r++) {
          size_t idx = (size_t)(grow0 + r) * DIM + gcol;
          outf[idx] = acc[i][j][r] + bias[gcol] + resid[idx];
        }
      } else {
#pragma unroll
        for (int r = 0; r < 4; r++) {
          float z = acc[i][j][r] + bias[gcol];
          float sg = 1.f / (1.f + __expf(-z));
          outq[(size_t)(grow0 + r) * MLPD + gcol] = (f16)(z * sg);
        }
      }
    }
  }
}

// ---------- flash attention, split-K + S^T trick + fixed-shift softmax ----------
// grid (SEQ/128, 2 kchunks, B*NH). Each wave: 32 q-rows (2 qtiles of 16),
// k-range [kc*1024, +1024) in 8 tiles of 128 (two 64-subtiles per barrier pair).
// Partials: op fp32 [kc][B*N][DIM], lp fp32 [kc][BH][SEQ]. No max shift.
__global__ __launch_bounds__(256, 4) void attn_kernel(const f16* __restrict__ qg,
    const f16* __restrict__ kg, const f16* __restrict__ vtg,
    float* __restrict__ op, float* __restrict__ lp) {
  __shared__ __align__(16) f16 Ks[2][64 * 64];   // [sub][kpos][d], chunk-swizzled
  __shared__ __align__(16) f16 Vs[2][64 * 64];   // [sub][d][kpos], chunk-swizzled
  const int bh = blockIdx.z, kc = blockIdx.y, q0 = blockIdx.x * 128;
  const int t = threadIdx.x, wave = t >> 6, lane = t & 63;
  const int n16 = lane & 15, quad = lane >> 4;
  const int srow = lane >> 3, spos = lane & 7;
  const f32x4 zero4 = {0.f, 0.f, 0.f, 0.f};

  // Q fragments (B-operand of 16x16x32): lane holds Q[qrow=n16][d=quad*8+j]
  half8 qf[2][2];
#pragma unroll
  for (int qt = 0; qt < 2; qt++) {
    const f16* qr = qg + ((size_t)bh * SEQ + q0 + wave * 32 + qt * 16 + n16) * HD + quad * 8;
    qf[qt][0] = *(const half8*)qr;
    qf[qt][1] = *(const half8*)(qr + 32);
  }

  // O^T accumulators: oc[qt][dt] holds Ot[d=dt*16+quad*4+r][qrow=qt*16+n16]
  f32x4 oc[2][4];
#pragma unroll
  for (int qt = 0; qt < 2; qt++)
#pragma unroll
    for (int dt = 0; dt < 4; dt++) oc[qt][dt] = zero4;
  float ls[2] = {0.f, 0.f};

  for (int kt128 = 0; kt128 < 8; kt128++) {
    const int kv0 = kc * 1024 + kt128 * 128;
    // stage 128 kpos of K and Vt as two 64-subtiles, one barrier pair for both
#pragma unroll
    for (int sub = 0; sub < 2; sub++)
#pragma unroll
      for (int p = 0; p < 2; p++) {
        int r = p * 32 + wave * 8 + srow;
        int c = spos ^ (r & 7);
        async_cp16(kg + ((size_t)bh * SEQ + kv0 + sub * 64 + r) * HD + c * 8,
                   &Ks[sub][p * 2048 + wave * 512]);
        async_cp16(vtg + ((size_t)bh * HD + r) * SEQ + kv0 + sub * 64 + c * 8,
                   &Vs[sub][p * 2048 + wave * 512]);
      }
    __syncthreads();

#pragma unroll
    for (int sub = 0; sub < 2; sub++) {
      // St = K * Q^T : C-layout St[kpos=kt*16+quad*4+r][qrow=qt*16+n16]
      f32x4 st[4][2];
#pragma unroll
      for (int kt = 0; kt < 4; kt++) {
        int row = kt * 16 + n16;
        half8 kf0 = *(const half8*)&Ks[sub][row * 64 + (quad ^ (row & 7)) * 8];
        half8 kf1 = *(const half8*)&Ks[sub][row * 64 + ((quad + 4) ^ (row & 7)) * 8];
#pragma unroll
        for (int qt = 0; qt < 2; qt++) {
          f32x4 z = zero4;
          z = __builtin_amdgcn_mfma_f32_16x16x32_f16(kf0, qf[qt][0], z, 0, 0, 0);
          z = __builtin_amdgcn_mfma_f32_16x16x32_f16(kf1, qf[qt][1], z, 0, 0, 0);
          st[kt][qt] = z;
        }
      }

      // p = exp2(St); accumulate l; P stays in registers as PV B-fragments
      half4 pf[2][4];
#pragma unroll
      for (int qt = 0; qt < 2; qt++)
#pragma unroll
        for (int kt = 0; kt < 4; kt++) {
          half4 p4;
          float s0 = __builtin_exp2f(st[kt][qt][0]);
          float s1 = __builtin_exp2f(st[kt][qt][1]);
          float s2 = __builtin_exp2f(st[kt][qt][2]);
          float s3 = __builtin_exp2f(st[kt][qt][3]);
          p4[0] = (f16)s0; p4[1] = (f16)s1; p4[2] = (f16)s2; p4[3] = (f16)s3;
          ls[qt] += (s0 + s1) + (s2 + s3);
          pf[qt][kt] = p4;
        }

      // O^T += Vt * P^T   (A = Vt frag from LDS b64, shared across qt; B = P in-reg)
#pragma unroll
      for (int kt = 0; kt < 4; kt++) {
        half4 va[4];
#pragma unroll
        for (int dt = 0; dt < 4; dt++) {
          int row = dt * 16 + n16;
          int phys = (kt * 2 + (quad >> 1)) ^ (row & 7);
          va[dt] = *(const half4*)&Vs[sub][row * 64 + phys * 8 + (quad & 1) * 4];
        }
#pragma unroll
        for (int dt = 0; dt < 4; dt++)
#pragma unroll
          for (int qt = 0; qt < 2; qt++)
            oc[qt][dt] = __builtin_amdgcn_mfma_f32_16x16x16f16(va[dt], pf[qt][kt], oc[qt][dt], 0, 0, 0);
      }
    }
    __syncthreads();
  }

  const int b = bh >> 4, h = bh & 15;
#pragma unroll
  for (int qt = 0; qt < 2; qt++) {
    // reduce l across quads (each quad held distinct kpos)
    float l = ls[qt];
    l += __shfl_xor(l, 16);
    l += __shfl_xor(l, 32);
    int q = q0 + wave * 32 + qt * 16 + n16;
    int row = b * SEQ + q;
#pragma unroll
    for (int dt = 0; dt < 4; dt++)
      *(f32x4*)&op[((size_t)kc * MROWS + row) * DIM + h * HD + dt * 16 + quad * 4] = oc[qt][dt];
    if (quad == 0) lp[((size_t)kc * BATCH * NH + bh) * SEQ + q] = l;
  }
}

// ---------- combine attn split-K partials: O = (O0+O1)/(l0+l1) -> f16 ----------
__global__ __launch_bounds__(256) void attn_reduce_kernel(const float* __restrict__ op,
    const float* __restrict__ lp, f16* __restrict__ obuf) {
  int row = blockIdx.x;            // b*SEQ + q
  int t = threadIdx.x;
  int b = row >> 11, q = row & 2047;
  int h = t >> 4;
  size_t base = (size_t)row * DIM + t * 4;
  float4 o1 = *(const float4*)&op[base];
  float4 o2 = *(const float4*)&op[(size_t)MROWS * DIM + base];
  size_t li = ((size_t)b * NH + h) * SEQ + q;
  float l = lp[li] + lp[(size_t)BATCH * NH * SEQ + li];
  float inv = 1.f / l;
  half4 o = { (f16)((o1.x + o2.x) * inv), (f16)((o1.y + o2.y) * inv),
              (f16)((o1.z + o2.z) * inv), (f16)((o1.w + o2.w) * inv) };
  *(half4*)&obuf[base] = o;
}

extern "C" void kernel_launch(void* const* d_in, const int* in_sizes, int n_in,
                              void* d_out, int out_size, void* d_ws, size_t ws_size,
                              hipStream_t stream) {
  const float* x     = (const float*)d_in[0];
  const float* qkv_w = (const float*)d_in[1];
  const float* out_w = (const float*)d_in[2];
  const float* out_b = (const float*)d_in[3];
  const float* ff_w1 = (const float*)d_in[4];
  const float* ff_b1 = (const float*)d_in[5];
  const float* ff_w2 = (const float*)d_in[6];
  const float* ff_b2 = (const float*)d_in[7];
  const float* ln1_w = (const float*)d_in[8];
  const float* ln1_b = (const float*)d_in[9];
  const float* ln2_w = (const float*)d_in[10];
  const float* ln2_b = (const float*)d_in[11];
  float* out = (float*)d_out;

  char* p = (char*)d_ws;
  size_t off = 0;
  auto alloc = [&](size_t bytes) {
    void* r = p + off;
    off += (bytes + 255) & ~(size_t)255;
    return r;
  };
  f16* wqkv = (f16*)alloc((size_t)3 * DIM * DIM * 2);
  f16* wout = (f16*)alloc((size_t)DIM * DIM * 2);
  f16* wf1  = (f16*)alloc((size_t)MLPD * DIM * 2);
  f16* wf2  = (f16*)alloc((size_t)MLPD * DIM * 2);
  f16* xln  = (f16*)alloc((size_t)MROWS * DIM * 2);
  f16* qb   = (f16*)alloc((size_t)MROWS * DIM * 2);
  f16* kb   = (f16*)alloc((size_t)MROWS * DIM * 2);
  f16* vtb  = (f16*)alloc((size_t)MROWS * DIM * 2);
  f16* obuf = (f16*)alloc((size_t)MROWS * DIM * 2);
  float* x1 = (float*)alloc((size_t)MROWS * DIM * 4);
  f16* hbuf = (f16*)alloc((size_t)MROWS * MLPD * 2);
  float* lp = (float*)alloc((size_t)2 * BATCH * NH * SEQ * 4);
  f16* x1ln = xln;            // xln dead after QKV gemm
  float* opa = (float*)hbuf;  // attn fp32 partials [2][MROWS][DIM]; dead before FF1

  cvt_all_kernel<<<12288, 256, 0, stream>>>(qkv_w, out_w, ff_w1, ff_w2,
                                            wqkv, wout, wf1, wf2);
  ln_kernel<<<MROWS, 256, 0, stream>>>(x, ln1_w, ln1_b, xln);
  gemm_bt<0, 128, 128><<<dim3(3 * DIM / 128, MROWS / 128), 256, 0, stream>>>(
      xln, wqkv, nullptr, nullptr, nullptr, qb, kb, vtb, DIM);
  attn_kernel<<<dim3(SEQ / 128, 2, BATCH * NH), 256, 0, stream>>>(qb, kb, vtb, opa, lp);
  attn_reduce_kernel<<<MROWS, 256, 0, stream>>>(opa, lp, obuf);
  gemm_bt<1, 64, 64><<<dim3(DIM / 64, MROWS / 64), 256, 0, stream>>>(
      obuf, wout, out_b, x, x1, nullptr, nullptr, nullptr, DIM);
  ln_kernel<<<MROWS, 256, 0, stream>>>(x1, ln2_w, ln2_b, x1ln);
  gemm_bt<2, 128, 128><<<dim3(MLPD / 128, MROWS / 128), 256, 0, stream>>>(
      x1ln, wf1, ff_b1, nullptr, nullptr, hbuf, nullptr, nullptr, DIM);
  gemm_bt<1, 64, 64><<<dim3(DIM / 64, MROWS / 64), 256, 0, stream>>>(
      hbuf, wf2, ff_b2, x1, out, nullptr, nullptr, nullptr, MLPD);
}

// Round 7
// 350.485 us; speedup vs baseline: 1.1892x; 1.1892x over previous
//
#include <hip/hip_runtime.h>
#include <stdint.h>

#define DIM   1024
#define NH    16
#define HD    64
#define SEQ   2048
#define BATCH 2
#define MROWS 4096   // B*N
#define MLPD  4096
#define LN_EPS 1e-5f
// attn scale 1/8 with log2(e) folded in: exp(x) = exp2(x*L2E)
#define QSCALE 0.18033688011112042f

typedef _Float16 f16;
typedef _Float16 half8 __attribute__((ext_vector_type(8)));
typedef _Float16 half4 __attribute__((ext_vector_type(4)));
typedef float f32x4 __attribute__((ext_vector_type(4)));

__device__ __forceinline__ void async_cp16(const void* g, void* l) {
  __builtin_amdgcn_global_load_lds(
      (const __attribute__((address_space(1))) unsigned int*)g,
      (__attribute__((address_space(3))) unsigned int*)l, 16, 0, 0);
}

// ---------- fused fp32 -> fp16 convert of all 4 weight matrices ----------
__global__ __launch_bounds__(256) void cvt_all_kernel(
    const float* __restrict__ w0, const float* __restrict__ w1,
    const float* __restrict__ w2, const float* __restrict__ w3,
    f16* __restrict__ d0, f16* __restrict__ d1, f16* __restrict__ d2,
    f16* __restrict__ d3) {
  int blk = blockIdx.x;
  const float* s;
  f16* d;
  int base;
  if (blk < 3072)      { s = w0; d = d0; base = blk; }
  else if (blk < 4096) { s = w1; d = d1; base = blk - 3072; }
  else if (blk < 8192) { s = w2; d = d2; base = blk - 4096; }
  else                 { s = w3; d = d3; base = blk - 8192; }
  int i = (base * 256 + threadIdx.x) * 4;
  float4 v = *(const float4*)(s + i);
  half4 o = { (f16)v.x, (f16)v.y, (f16)v.z, (f16)v.w };
  *(half4*)(d + i) = o;
}

// ---------- LayerNorm: fp32 [rows,1024] -> fp16 ----------
__global__ __launch_bounds__(256) void ln_kernel(const float* __restrict__ x,
    const float* __restrict__ w, const float* __restrict__ b, f16* __restrict__ out) {
  __shared__ float red[8];
  int row = blockIdx.x, t = threadIdx.x;
  const float4 v = ((const float4*)(x + (size_t)row * DIM))[t];
  float s1 = v.x + v.y + v.z + v.w;
  float s2 = v.x * v.x + v.y * v.y + v.z * v.z + v.w * v.w;
#pragma unroll
  for (int m = 32; m; m >>= 1) { s1 += __shfl_xor(s1, m); s2 += __shfl_xor(s2, m); }
  if ((t & 63) == 0) { red[t >> 6] = s1; red[4 + (t >> 6)] = s2; }
  __syncthreads();
  s1 = red[0] + red[1] + red[2] + red[3];
  s2 = red[4] + red[5] + red[6] + red[7];
  float mu = s1 * (1.f / DIM);
  float rs = rsqrtf(s2 * (1.f / DIM) - mu * mu + LN_EPS);
  float4 wv = ((const float4*)w)[t];
  float4 bv = ((const float4*)b)[t];
  half4 o = { (f16)((v.x - mu) * rs * wv.x + bv.x), (f16)((v.y - mu) * rs * wv.y + bv.y),
              (f16)((v.z - mu) * rs * wv.z + bv.z), (f16)((v.w - mu) * rs * wv.w + bv.w) };
  ((half4*)(out + (size_t)row * DIM))[t] = o;
}

// ---------- GEMM  C[M,N] = A[M,K] @ W[N,K]^T  (both K-major fp16) ----------
// MODE 0: QKV scatter: q*QSCALE, k -> [B,H,N,64]; v -> TRANSPOSED [B,H,64,N]
// MODE 1: out = acc + bias[col] + resid[row,col]  (fp32 out, N-stride DIM)
// MODE 2: out = f16(silu(acc + bias[col]))        (fp16 out, stride MLPD)
// GSWAP: 1 -> blockIdx.x = tile_m (pins A-panels to one XCD's L2)
template <int MODE, int TM, int TN, int BK, int GSWAP>
__global__ __launch_bounds__(256, (TN == 64) ? 4 : 1) void gemm_bt(
    const f16* __restrict__ A, const f16* __restrict__ W,
    const float* __restrict__ bias, const float* __restrict__ resid,
    float* __restrict__ outf, f16* __restrict__ outq, f16* __restrict__ outk,
    f16* __restrict__ outv, int K) {
  constexpr int IT = (TN == 128) ? (TM / 32) : (TM / 64);  // i-tiles per wave
  constexpr int MSUB = IT * 16;                            // m-rows per wave
  constexpr int CPR = BK / 8;                              // 16B chunks per row
  constexpr int RPP = 256 / CPR;                           // rows staged per pass
  __shared__ __align__(16) f16 As[TM * BK];
  __shared__ __align__(16) f16 Bs[TN * BK];
  const int t = threadIdx.x;
  const int wave = t >> 6, lane = t & 63;
  const int n16 = lane & 15, quad = lane >> 4;
  const int tile_m = (GSWAP ? blockIdx.x : blockIdx.y) * TM;
  const int tile_n = (GSWAP ? blockIdx.y : blockIdx.x) * TN;
  const int wm = (TN == 128) ? (wave >> 1) : wave;
  const int wn = (TN == 128) ? (wave & 1) : 0;
  const int srow = lane / CPR, spos = lane & (CPR - 1);
  const f32x4 zero4 = {0.f, 0.f, 0.f, 0.f};

  f32x4 acc[IT][4];
#pragma unroll
  for (int i = 0; i < IT; i++)
#pragma unroll
    for (int j = 0; j < 4; j++) acc[i][j] = zero4;

  for (int k0 = 0; k0 < K; k0 += BK) {
    // stage A-tile (TMxBK) and B-tile (TNxBK), XOR-swizzled 16B chunks
#pragma unroll
    for (int q = 0; q < TM / RPP; q++) {
      int r = q * RPP + wave * (64 / CPR) + srow;
      int c = spos ^ (r & (CPR - 1));
      async_cp16(A + (size_t)(tile_m + r) * K + k0 + c * 8, &As[q * 2048 + wave * 512]);
    }
#pragma unroll
    for (int q = 0; q < TN / RPP; q++) {
      int r = q * RPP + wave * (64 / CPR) + srow;
      int c = spos ^ (r & (CPR - 1));
      async_cp16(W + (size_t)(tile_n + r) * K + k0 + c * 8, &Bs[q * 2048 + wave * 512]);
    }
    __syncthreads();
#pragma unroll
    for (int kk = 0; kk < BK / 32; kk++) {
      half8 af[IT], bfr[4];
#pragma unroll
      for (int i = 0; i < IT; i++) {
        int row = wm * MSUB + i * 16 + n16;
        int c = (kk * 4 + quad) ^ (row & (CPR - 1));
        af[i] = *(const half8*)&As[row * BK + c * 8];
      }
#pragma unroll
      for (int j = 0; j < 4; j++) {
        int row = wn * 64 + j * 16 + n16;
        int c = (kk * 4 + quad) ^ (row & (CPR - 1));
        bfr[j] = *(const half8*)&Bs[row * BK + c * 8];
      }
#pragma unroll
      for (int i = 0; i < IT; i++)
#pragma unroll
        for (int j = 0; j < 4; j++)
          acc[i][j] = __builtin_amdgcn_mfma_f32_16x16x32_f16(af[i], bfr[j], acc[i][j], 0, 0, 0);
    }
    __syncthreads();
  }

#pragma unroll
  for (int i = 0; i < IT; i++) {
#pragma unroll
    for (int j = 0; j < 4; j++) {
      int gcol = tile_n + wn * 64 + j * 16 + n16;
      int grow0 = tile_m + wm * MSUB + i * 16 + quad * 4;
      if constexpr (MODE == 0) {
        int tsel = gcol >> 10, h = (gcol >> 6) & 15, d = gcol & 63;
        int bb = grow0 >> 11, nn0 = grow0 & 2047;
        if (tsel == 2) {
          // V transposed: vt[((bb*NH+h)*HD+d)*SEQ + nn], 4 consecutive nn
          half4 o;
#pragma unroll
          for (int r = 0; r < 4; r++) o[r] = (f16)acc[i][j][r];
          *(half4*)&outv[(((size_t)bb * NH + h) * HD + d) * SEQ + nn0] = o;
        } else {
          f16* dst = (tsel == 0) ? outq : outk;
          float sc = (tsel == 0) ? QSCALE : 1.0f;
#pragma unroll
          for (int r = 0; r < 4; r++)
            dst[(((size_t)bb * NH + h) * SEQ + nn0 + r) * HD + d] = (f16)(acc[i][j][r] * sc);
        }
      } else if constexpr (MODE == 1) {
#pragma unroll
        for (int r = 0; r < 4; r++) {
          size_t idx = (size_t)(grow0 + r) * DIM + gcol;
          outf[idx] = acc[i][j][r] + bias[gcol] + resid[idx];
        }
      } else {
#pragma unroll
        for (int r = 0; r < 4; r++) {
          float z = acc[i][j][r] + bias[gcol];
          float sg = 1.f / (1.f + __expf(-z));
          outq[(size_t)(grow0 + r) * MLPD + gcol] = (f16)(z * sg);
        }
      }
    }
  }
}

// ---------- flash attention, split-K + S^T trick + fixed-shift softmax ----------
// grid (SEQ/128, 2 kchunks, B*NH). Each wave: 32 q-rows (2 qtiles of 16),
// k-range [kc*1024, +1024) in 16 tiles of 64. Partials: op fp32 [kc][B*N][DIM],
// lp fp32 [kc][BH][SEQ]. No max shift (scores bounded; shift cancels in O/l).
__global__ __launch_bounds__(256, 4) void attn_kernel(const f16* __restrict__ qg,
    const f16* __restrict__ kg, const f16* __restrict__ vtg,
    float* __restrict__ op, float* __restrict__ lp) {
  __shared__ __align__(16) f16 Ks[64 * 64];   // [kpos][d], chunk-swizzled
  __shared__ __align__(16) f16 Vs[64 * 64];   // [d][kpos], chunk-swizzled
  const int bh = blockIdx.z, kc = blockIdx.y, q0 = blockIdx.x * 128;
  const int t = threadIdx.x, wave = t >> 6, lane = t & 63;
  const int n16 = lane & 15, quad = lane >> 4;
  const int srow = lane >> 3, spos = lane & 7;
  const f32x4 zero4 = {0.f, 0.f, 0.f, 0.f};

  // Q fragments (B-operand of 16x16x32): lane holds Q[qrow=n16][d=quad*8+j]
  half8 qf[2][2];
#pragma unroll
  for (int qt = 0; qt < 2; qt++) {
    const f16* qr = qg + ((size_t)bh * SEQ + q0 + wave * 32 + qt * 16 + n16) * HD + quad * 8;
    qf[qt][0] = *(const half8*)qr;
    qf[qt][1] = *(const half8*)(qr + 32);
  }

  // O^T accumulators: oc[qt][dt] holds Ot[d=dt*16+quad*4+r][qrow=qt*16+n16]
  f32x4 oc[2][4];
#pragma unroll
  for (int qt = 0; qt < 2; qt++)
#pragma unroll
    for (int dt = 0; dt < 4; dt++) oc[qt][dt] = zero4;
  float ls[2] = {0.f, 0.f};

  for (int kt64 = 0; kt64 < 16; kt64++) {
    const int kv0 = kc * 1024 + kt64 * 64;
    // stage K (64 kpos x 64 d) and Vt (64 d x 64 kpos), swizzled 16B chunks
#pragma unroll
    for (int p = 0; p < 2; p++) {
      int r = p * 32 + wave * 8 + srow;
      int c = spos ^ (r & 7);
      async_cp16(kg + ((size_t)bh * SEQ + kv0 + r) * HD + c * 8, &Ks[p * 2048 + wave * 512]);
      async_cp16(vtg + ((size_t)bh * HD + r) * SEQ + kv0 + c * 8, &Vs[p * 2048 + wave * 512]);
    }
    __syncthreads();

    // St = K * Q^T : C-layout St[kpos=kt*16+quad*4+r][qrow=qt*16+n16]
    f32x4 st[4][2];
#pragma unroll
    for (int kt = 0; kt < 4; kt++) {
      int row = kt * 16 + n16;
      half8 kf0 = *(const half8*)&Ks[row * 64 + (quad ^ (row & 7)) * 8];
      half8 kf1 = *(const half8*)&Ks[row * 64 + ((quad + 4) ^ (row & 7)) * 8];
#pragma unroll
      for (int qt = 0; qt < 2; qt++) {
        f32x4 z = zero4;
        z = __builtin_amdgcn_mfma_f32_16x16x32_f16(kf0, qf[qt][0], z, 0, 0, 0);
        z = __builtin_amdgcn_mfma_f32_16x16x32_f16(kf1, qf[qt][1], z, 0, 0, 0);
        st[kt][qt] = z;
      }
    }

    // p = exp2(St); accumulate l; P stays in registers as PV B-fragments
    half4 pf[2][4];
#pragma unroll
    for (int qt = 0; qt < 2; qt++)
#pragma unroll
      for (int kt = 0; kt < 4; kt++) {
        half4 p4;
        float s0 = __builtin_exp2f(st[kt][qt][0]);
        float s1 = __builtin_exp2f(st[kt][qt][1]);
        float s2 = __builtin_exp2f(st[kt][qt][2]);
        float s3 = __builtin_exp2f(st[kt][qt][3]);
        p4[0] = (f16)s0; p4[1] = (f16)s1; p4[2] = (f16)s2; p4[3] = (f16)s3;
        ls[qt] += (s0 + s1) + (s2 + s3);
        pf[qt][kt] = p4;
      }

    // O^T += Vt * P^T   (A = Vt frag from LDS b64, shared across qt; B = P in-reg)
#pragma unroll
    for (int kt = 0; kt < 4; kt++) {
      half4 va[4];
#pragma unroll
      for (int dt = 0; dt < 4; dt++) {
        int row = dt * 16 + n16;
        int phys = (kt * 2 + (quad >> 1)) ^ (row & 7);
        va[dt] = *(const half4*)&Vs[row * 64 + phys * 8 + (quad & 1) * 4];
      }
#pragma unroll
      for (int dt = 0; dt < 4; dt++)
#pragma unroll
        for (int qt = 0; qt < 2; qt++)
          oc[qt][dt] = __builtin_amdgcn_mfma_f32_16x16x16f16(va[dt], pf[qt][kt], oc[qt][dt], 0, 0, 0);
    }
    __syncthreads();
  }

  const int b = bh >> 4, h = bh & 15;
#pragma unroll
  for (int qt = 0; qt < 2; qt++) {
    // reduce l across quads (each quad held distinct kpos)
    float l = ls[qt];
    l += __shfl_xor(l, 16);
    l += __shfl_xor(l, 32);
    int q = q0 + wave * 32 + qt * 16 + n16;
    int row = b * SEQ + q;
#pragma unroll
    for (int dt = 0; dt < 4; dt++)
      *(f32x4*)&op[((size_t)kc * MROWS + row) * DIM + h * HD + dt * 16 + quad * 4] = oc[qt][dt];
    if (quad == 0) lp[((size_t)kc * BATCH * NH + bh) * SEQ + q] = l;
  }
}

// ---------- combine attn split-K partials: O = (O0+O1)/(l0+l1) -> f16 ----------
__global__ __launch_bounds__(256) void attn_reduce_kernel(const float* __restrict__ op,
    const float* __restrict__ lp, f16* __restrict__ obuf) {
  int row = blockIdx.x;            // b*SEQ + q
  int t = threadIdx.x;
  int b = row >> 11, q = row & 2047;
  int h = t >> 4;
  size_t base = (size_t)row * DIM + t * 4;
  float4 o1 = *(const float4*)&op[base];
  float4 o2 = *(const float4*)&op[(size_t)MROWS * DIM + base];
  size_t li = ((size_t)b * NH + h) * SEQ + q;
  float l = lp[li] + lp[(size_t)BATCH * NH * SEQ + li];
  float inv = 1.f / l;
  half4 o = { (f16)((o1.x + o2.x) * inv), (f16)((o1.y + o2.y) * inv),
              (f16)((o1.z + o2.z) * inv), (f16)((o1.w + o2.w) * inv) };
  *(half4*)&obuf[base] = o;
}

extern "C" void kernel_launch(void* const* d_in, const int* in_sizes, int n_in,
                              void* d_out, int out_size, void* d_ws, size_t ws_size,
                              hipStream_t stream) {
  const float* x     = (const float*)d_in[0];
  const float* qkv_w = (const float*)d_in[1];
  const float* out_w = (const float*)d_in[2];
  const float* out_b = (const float*)d_in[3];
  const float* ff_w1 = (const float*)d_in[4];
  const float* ff_b1 = (const float*)d_in[5];
  const float* ff_w2 = (const float*)d_in[6];
  const float* ff_b2 = (const float*)d_in[7];
  const float* ln1_w = (const float*)d_in[8];
  const float* ln1_b = (const float*)d_in[9];
  const float* ln2_w = (const float*)d_in[10];
  const float* ln2_b = (const float*)d_in[11];
  float* out = (float*)d_out;

  char* p = (char*)d_ws;
  size_t off = 0;
  auto alloc = [&](size_t bytes) {
    void* r = p + off;
    off += (bytes + 255) & ~(size_t)255;
    return r;
  };
  f16* wqkv = (f16*)alloc((size_t)3 * DIM * DIM * 2);
  f16* wout = (f16*)alloc((size_t)DIM * DIM * 2);
  f16* wf1  = (f16*)alloc((size_t)MLPD * DIM * 2);
  f16* wf2  = (f16*)alloc((size_t)MLPD * DIM * 2);
  f16* xln  = (f16*)alloc((size_t)MROWS * DIM * 2);
  f16* qb   = (f16*)alloc((size_t)MROWS * DIM * 2);
  f16* kb   = (f16*)alloc((size_t)MROWS * DIM * 2);
  f16* vtb  = (f16*)alloc((size_t)MROWS * DIM * 2);
  f16* obuf = (f16*)alloc((size_t)MROWS * DIM * 2);
  float* x1 = (float*)alloc((size_t)MROWS * DIM * 4);
  f16* hbuf = (f16*)alloc((size_t)MROWS * MLPD * 2);
  float* lp = (float*)alloc((size_t)2 * BATCH * NH * SEQ * 4);
  f16* x1ln = xln;            // xln dead after QKV gemm
  float* opa = (float*)hbuf;  // attn fp32 partials [2][MROWS][DIM]; dead before FF1

  cvt_all_kernel<<<12288, 256, 0, stream>>>(qkv_w, out_w, ff_w1, ff_w2,
                                            wqkv, wout, wf1, wf2);
  ln_kernel<<<MROWS, 256, 0, stream>>>(x, ln1_w, ln1_b, xln);
  gemm_bt<0, 128, 128, 64, 0><<<dim3(3 * DIM / 128, MROWS / 128), 256, 0, stream>>>(
      xln, wqkv, nullptr, nullptr, nullptr, qb, kb, vtb, DIM);
  attn_kernel<<<dim3(SEQ / 128, 2, BATCH * NH), 256, 0, stream>>>(qb, kb, vtb, opa, lp);
  attn_reduce_kernel<<<MROWS, 256, 0, stream>>>(opa, lp, obuf);
  gemm_bt<1, 128, 64, 128, 1><<<dim3(MROWS / 128, DIM / 64), 256, 0, stream>>>(
      obuf, wout, out_b, x, x1, nullptr, nullptr, nullptr, DIM);
  ln_kernel<<<MROWS, 256, 0, stream>>>(x1, ln2_w, ln2_b, x1ln);
  gemm_bt<2, 128, 128, 64, 0><<<dim3(MLPD / 128, MROWS / 128), 256, 0, stream>>>(
      x1ln, wf1, ff_b1, nullptr, nullptr, hbuf, nullptr, nullptr, DIM);
  gemm_bt<1, 128, 64, 128, 1><<<dim3(MROWS / 128, DIM / 64), 256, 0, stream>>>(
      hbuf, wf2, ff_b2, x1, out, nullptr, nullptr, nullptr, MLPD);
}